// Round 13
// baseline (122.890 us; speedup 1.0000x reference)
//
#include <hip/hip_runtime.h>
#include <stdint.h>

#define VOCAB 21128
#define NUMC  53
#define EMB   128
#define SEQ   512
#define BATCH 512

typedef __bf16 bf16x8 __attribute__((ext_vector_type(8)));
typedef float f32x4 __attribute__((ext_vector_type(4)));

__device__ __forceinline__ unsigned int f2bf1(float f) {
    union { float f; unsigned int u; } v; v.f = f;
    return (v.u + 0x7FFFu + ((v.u >> 16) & 1u)) >> 16;
}
__device__ __forceinline__ unsigned int pack2(float a, float b) {
    return f2bf1(a) | (f2bf1(b) << 16);
}
__device__ __forceinline__ float b2f(unsigned short u) {
    union { float f; unsigned int i; } v; v.i = ((unsigned int)u) << 16; return v.f;
}

// Prep (VERBATIM from the proven anchor): emb fp32 -> bf16 Tb[VOCAB][128];
// conv_w -> Wp bf16 in per-lane B-fragment order (16x16x32, session-verified):
// Wp[s 0..11][g 0..7][lane 0..63][j 0..7] = w[f=g*16+(lane&15)][e=kk&127][tap=kk>>7],
// kk = s*32 + (lane>>4)*8 + j.
__global__ void prep_kernel(const float* __restrict__ emb, const float* __restrict__ cw,
                            unsigned short* __restrict__ Tb, unsigned short* __restrict__ Wp) {
    int idx = blockIdx.x * blockDim.x + threadIdx.x;
    const int n8 = VOCAB * EMB / 8;  // 338048
    if (idx < n8) {
        const float4* src = (const float4*)emb + (size_t)idx * 2;
        float4 a = src[0], b = src[1];
        uint4 o;
        o.x = pack2(a.x, a.y);
        o.y = pack2(a.z, a.w);
        o.z = pack2(b.x, b.y);
        o.w = pack2(b.z, b.w);
        *(uint4*)(Tb + (size_t)idx * 8) = o;
    }
    if (idx < 12 * 8 * 64 * 8) {
        int j = idx & 7, l = (idx >> 3) & 63, g = (idx >> 9) & 7, s = idx >> 12;
        int kk = s * 32 + (l >> 4) * 8 + j;
        int f = g * 16 + (l & 15);
        int tap = kk >> 7, e = kk & 127;
        Wp[idx] = (unsigned short)f2bf1(cw[(f * EMB + e) * 3 + tap]);
    }
}

// Vocabulary-factored conv (r11 structure, r12 fixes):
//   out[f,l] = sum_k P[cid[l+k-1]][k][f],  P[id][k][f] = sum_e emb[id,e]*w[f,e,k]
// P = VOCAB x 384 bf16 (16.2 MB). Anchor's MFMA loop with (1) A read directly
// from Tb (no +tap row shift, linear chunk q, no LDS) and (2) accumulator split
// per tap: acc[s>>2][mt][nt]. B loads = anchor's verbatim Wp lines. C store =
// anchor-verified mapping (row=quad*4+reg, col=lc). bf16 P store adds <=6e-4
// error (threshold 4.1e-3, anchor at 9.8e-4). Tb row 0 = zeros -> P row 0 = 0
// = conv zero-padding. Rows >= VOCAB read in-ws garbage (row-independent in
// MFMA) and are discarded by the store guard.
__launch_bounds__(256)
__global__ void pcnn_vgemm(const unsigned short* __restrict__ Tb,
                           const unsigned short* __restrict__ Wp,
                           unsigned short* __restrict__ P) {
    const int tid  = threadIdx.x;
    const int lane = tid & 63;
    const int wn   = tid >> 6;   // 0..3 filter group (32 filters)
    const int quad = lane >> 4;
    const int lc   = lane & 15;
    const int row0 = blockIdx.x * 64;

    f32x4 acc[3][4][2];
#pragma unroll
    for (int t = 0; t < 3; ++t)
#pragma unroll
        for (int mt = 0; mt < 4; ++mt)
#pragma unroll
            for (int nt = 0; nt < 2; ++nt)
                acc[t][mt][nt] = (f32x4){0.f, 0.f, 0.f, 0.f};

#pragma unroll
    for (int s = 0; s < 12; ++s) {
        const int tap = s >> 2;                      // compile-time per unrolled s
        const int q   = (s & 3) * 4 + quad;          // e-octet within the 128-e row
        bf16x8 b0 = *(const bf16x8*)(Wp + (size_t)((s * 8 + wn * 2) * 64 + lane) * 8);
        bf16x8 b1 = *(const bf16x8*)(Wp + (size_t)((s * 8 + wn * 2 + 1) * 64 + lane) * 8);
#pragma unroll
        for (int mt = 0; mt < 4; ++mt) {
            bf16x8 a = *(const bf16x8*)(Tb + (size_t)(row0 + mt * 16 + lc) * 128 + q * 8);
            acc[tap][mt][0] = __builtin_amdgcn_mfma_f32_16x16x32_bf16(a, b0, acc[tap][mt][0], 0, 0, 0);
            acc[tap][mt][1] = __builtin_amdgcn_mfma_f32_16x16x32_bf16(a, b1, acc[tap][mt][1], 0, 0, 0);
        }
    }

    // Store P[gr][tap*128 + f] bf16; C mapping row=quad*4+reg, col=lc (verified).
#pragma unroll
    for (int tap = 0; tap < 3; ++tap)
#pragma unroll
        for (int mt = 0; mt < 4; ++mt) {
            int grb = row0 + mt * 16 + quad * 4;
#pragma unroll
            for (int nt = 0; nt < 2; ++nt) {
                int col = tap * 128 + (wn * 2 + nt) * 16 + lc;
#pragma unroll
                for (int reg = 0; reg < 4; ++reg) {
                    int gr = grb + reg;
                    if (gr < VOCAB)
                        P[(size_t)gr * 384 + col] = (unsigned short)f2bf1(acc[tap][mt][nt][reg]);
                }
            }
        }
}

// 2048 blocks: block (b, tq) = batch row b, positions [tq*128, +128).
// 256 threads: f = tid&127, half = tid>>7 (even/odd position). Per position:
// 3 bf16 lookups into L3-resident P (per wave per tap: 64 consecutive bf16 =
// one 128 B line, fully coalesced, zero amplification), fp32 sum, masked
// 3-segment max in registers. No LDS staging, no DMA, no MFMA; 8 blocks/CU,
// 32 waves/CU all resident.
// r12 FIX (the r10/r11 failure): the Pd export below is a strided loop over
// all 384 columns — the previous `if (tid < 384)` guard under a 256-thread
// block only covered s3 in {0,1}, leaving Pd's segment-3 plane as poison
// (NaN -> fmaxf-killed -> silently dropped from the FC; identical absmax both
// rounds because the error was P-value-independent).
__launch_bounds__(256)
__global__ void pcnn_gather(const int* __restrict__ cid, const int* __restrict__ p1,
                            const int* __restrict__ p2,
                            const unsigned short* __restrict__ P,
                            float* __restrict__ Pd) {
    __shared__ int idsB[130];
    __shared__ float pstage[2][3][128];

    const int bx  = blockIdx.x;
    const int b   = bx >> 2;
    const int tq  = bx & 3;
    const int tid = threadIdx.x;

    const int* crow = cid + (size_t)b * SEQ;
    if (tid < 130) {
        int p = tq * 128 + tid - 1;                 // idsB[i] = id at pos tq*128+i-1
        unsigned int id = (p >= 0 && p < SEQ) ? (unsigned int)crow[p] : 0u;
        idsB[tid] = (int)(id * 768u);               // byte offset of bf16 P row
    }

    int e1 = min(p1[b], p2[b]);
    int e2 = max(p1[b], p2[b]);
    if (e1 == e2) e2 = min(e1 + 1, SEQ);
    const int e1m = max(e1, 1);

    __syncthreads();

    const int f    = tid & 127;
    const int half = tid >> 7;
    const char* Pb = (const char*)P;
    const int o0 = f * 2;            // tap 0: id at l-1
    const int o1 = 256 + f * 2;      // tap 1: id at l
    const int o2 = 512 + f * 2;      // tap 2: id at l+1

    float smax0 = -1e30f, smax1 = -1e30f, smax2 = -1e30f;

#pragma unroll 4
    for (int pass = 0; pass < 64; ++pass) {
        int ll = pass * 2 + half;                   // local position 0..127
        int p  = tq * 128 + ll;
        float v = b2f(*(const unsigned short*)(Pb + idsB[ll]     + o0))
                + b2f(*(const unsigned short*)(Pb + idsB[ll + 1] + o1))
                + b2f(*(const unsigned short*)(Pb + idsB[ll + 2] + o2));
        smax0 = fmaxf(smax0, v + ((p < e1m)           ? 0.f : -2e30f));
        smax1 = fmaxf(smax1, v + ((p >= e1 && p < e2) ? 0.f : -2e30f));
        smax2 = fmaxf(smax2, v + ((p >= e2)           ? 0.f : -2e30f));
    }

    pstage[half][0][f] = smax0;
    pstage[half][1][f] = smax1;
    pstage[half][2][f] = smax2;
    __syncthreads();

    // FIXED export: strided loop covers all 384 columns with 256 threads.
    for (int j = tid; j < 384; j += 256) {
        int s3 = j >> 7, ff = j & 127;
        Pd[((size_t)b * 4 + tq) * 384 + j] = fmaxf(pstage[0][s3][ff], pstage[1][s3][ff]);
    }
}

// Combine: max over the 4 tile-partials, bias+ReLU, FC 384->53. One block per
// row. Byte-identical to the proven anchor's combine.
__launch_bounds__(256)
__global__ void pcnn_combine(const float* __restrict__ Pd, const float* __restrict__ cb,
                             const float* __restrict__ fcw, const float* __restrict__ fcb,
                             float* __restrict__ out) {
    __shared__ float pooled[384];
    __shared__ float fcred[NUMC][4];
    const int b = blockIdx.x;
    const int tid = threadIdx.x;

    for (int j = tid; j < 384; j += 256) {
        const float* pp = Pd + (size_t)b * 4 * 384 + j;
        float m = fmaxf(fmaxf(pp[0], pp[384]), fmaxf(pp[768], pp[1152]));
        pooled[j] = fmaxf(m + cb[j & 127], 0.f);
    }
    __syncthreads();

    if (tid < 212) {
        int c = tid >> 2, q = tid & 3;
        const float* wrow = fcw + (size_t)c * 384 + q * 96;
        const float* pp   = pooled + q * 96;
        float sum = 0.f;
#pragma unroll 8
        for (int i = 0; i < 96; ++i) sum += wrow[i] * pp[i];
        fcred[c][q] = sum;
    }
    __syncthreads();
    if (tid < NUMC)
        out[(size_t)b * NUMC + tid] =
            fcred[tid][0] + fcred[tid][1] + fcred[tid][2] + fcred[tid][3] + fcb[tid];
}

extern "C" void kernel_launch(void* const* d_in, const int* in_sizes, int n_in,
                              void* d_out, int out_size, void* d_ws, size_t ws_size,
                              hipStream_t stream) {
    const int*   cid = (const int*)d_in[0];
    const int*   p1  = (const int*)d_in[1];
    const int*   p2  = (const int*)d_in[2];
    const float* emb = (const float*)d_in[3];
    const float* cw  = (const float*)d_in[4];
    const float* cb  = (const float*)d_in[5];
    const float* fcw = (const float*)d_in[6];
    const float* fcb = (const float*)d_in[7];
    float* out = (float*)d_out;

    // ws: Tb bf16 [VOCAB*128] (5,408,768 B) | Wp bf16 [49152] (98,304 B)
    //   | P bf16 [VOCAB*384] (16,226,304 B) | Pd fp32 [512*4*384] (3,145,728 B)
    unsigned short* Tb = (unsigned short*)d_ws;
    unsigned short* Wp = (unsigned short*)((char*)d_ws + (size_t)VOCAB * EMB * 2);
    unsigned short* P  = (unsigned short*)((char*)d_ws + (size_t)VOCAB * EMB * 2 + 98304);
    float*          Pd = (float*)((char*)d_ws + (size_t)VOCAB * EMB * 2 + 98304
                                  + (size_t)VOCAB * 384 * 2);

    const int n8 = VOCAB * EMB / 8;
    const int prep_threads = 256;
    const int prep_blocks  = (n8 + prep_threads - 1) / prep_threads;
    const int gemm_blocks  = (VOCAB + 63) / 64;  // 331
    prep_kernel<<<prep_blocks, prep_threads, 0, stream>>>(emb, cw, Tb, Wp);
    pcnn_vgemm<<<gemm_blocks, 256, 0, stream>>>(Tb, Wp, P);
    pcnn_gather<<<BATCH * 4, 256, 0, stream>>>(cid, p1, p2, P, Pd);
    pcnn_combine<<<BATCH, 256, 0, stream>>>(Pd, cb, fcw, fcb, out);
}

// Round 15
// 115.781 us; speedup vs baseline: 1.0614x; 1.0614x over previous
//
#include <hip/hip_runtime.h>
#include <stdint.h>

#define VOCAB 21128
#define NUMC  53
#define EMB   128
#define SEQ   512
#define BATCH 512

typedef __bf16 bf16x8 __attribute__((ext_vector_type(8)));
typedef float f32x4 __attribute__((ext_vector_type(4)));

__device__ __forceinline__ unsigned int f2bf1(float f) {
    union { float f; unsigned int u; } v; v.f = f;
    return (v.u + 0x7FFFu + ((v.u >> 16) & 1u)) >> 16;
}
__device__ __forceinline__ unsigned int pack2(float a, float b) {
    return f2bf1(a) | (f2bf1(b) << 16);
}
__device__ __forceinline__ float b2f(unsigned short u) {
    union { float f; unsigned int i; } v; v.i = ((unsigned int)u) << 16; return v.f;
}

// Wp-only prep (anchor's verified Wp pass; Tb is gone — vgemm reads emb direct):
// Wp[s 0..11][g 0..7][lane 0..63][j 0..7] = w[f=g*16+(lane&15)][e=kk&127][tap=kk>>7],
// kk = s*32 + (lane>>4)*8 + j.
__global__ void prep_w(const float* __restrict__ cw, unsigned short* __restrict__ Wp) {
    int idx = blockIdx.x * blockDim.x + threadIdx.x;
    if (idx < 12 * 8 * 64 * 8) {
        int j = idx & 7, l = (idx >> 3) & 63, g = (idx >> 9) & 7, s = idx >> 12;
        int kk = s * 32 + (l >> 4) * 8 + j;
        int f = g * 16 + (l & 15);
        int tap = kk >> 7, e = kk & 127;
        Wp[idx] = (unsigned short)f2bf1(cw[(f * EMB + e) * 3 + tap]);
    }
}

// Vocabulary-factored conv (r13-verified algebra, passed at absmax 9.77e-4):
//   out[f,l] = sum_k P[cid[l+k-1]][k][f],  P[id][k][f] = sum_e emb[id,e]*w[f,e,k]
// P = VOCAB x 384 bf16 (16.2 MB). A staged directly from fp32 emb (r10's
// staging, exonerated by r12 forensics: the r10/r11 bug was the export guard),
// packed bf16 into XOR-swizzled LDS (slot (r, c^(r&15)) holds chunk c).
// B loads = anchor's verbatim Wp lines. Accumulator split per tap (s>>2).
// C store = anchor-verified mapping (row=quad*4+reg, col=lc). emb row 0 = 0
// -> P row 0 = 0 = conv zero-padding. Rows >= VOCAB: staged as zeros, store
// guarded.
__launch_bounds__(256)
__global__ void pcnn_vgemm(const float* __restrict__ emb,
                           const unsigned short* __restrict__ Wp,
                           unsigned short* __restrict__ P) {
    __shared__ __align__(16) unsigned short As[64 * 128];  // 16 KB, swizzled

    const int tid  = threadIdx.x;
    const int lane = tid & 63;
    const int wn   = tid >> 6;   // 0..3 filter group pair
    const int quad = lane >> 4;
    const int lc   = lane & 15;
    const int row0 = blockIdx.x * 64;

    // Stage A: 64 rows x 16 chunks (8 bf16 = 16 B) = 1024 tasks, 4 passes.
#pragma unroll
    for (int i = 0; i < 4; ++i) {
        int task = tid + 256 * i;
        int r = task >> 4, c = task & 15;
        int gr = row0 + r;
        uint4 o = {0u, 0u, 0u, 0u};
        if (gr < VOCAB) {
            const float4* src = (const float4*)(emb + (size_t)gr * EMB + c * 8);
            float4 a = src[0], b = src[1];
            o.x = pack2(a.x, a.y); o.y = pack2(a.z, a.w);
            o.z = pack2(b.x, b.y); o.w = pack2(b.z, b.w);
        }
        *(uint4*)((char*)As + (r * 16 + (c ^ (r & 15))) * 16) = o;
    }
    __syncthreads();

    f32x4 acc[3][4][2];
#pragma unroll
    for (int t = 0; t < 3; ++t)
#pragma unroll
        for (int mt = 0; mt < 4; ++mt)
#pragma unroll
            for (int nt = 0; nt < 2; ++nt)
                acc[t][mt][nt] = (f32x4){0.f, 0.f, 0.f, 0.f};

#pragma unroll
    for (int s = 0; s < 12; ++s) {
        const int tap = s >> 2;                      // compile-time per unrolled s
        const int q   = (s & 3) * 4 + quad;          // e-octet within the 128-e row
        bf16x8 b0 = *(const bf16x8*)(Wp + (size_t)((s * 8 + wn * 2) * 64 + lane) * 8);
        bf16x8 b1 = *(const bf16x8*)(Wp + (size_t)((s * 8 + wn * 2 + 1) * 64 + lane) * 8);
#pragma unroll
        for (int mt = 0; mt < 4; ++mt) {
            int r = mt * 16 + lc;
            bf16x8 a = *(const bf16x8*)(As + r * 128 + (q ^ (r & 15)) * 8);
            acc[tap][mt][0] = __builtin_amdgcn_mfma_f32_16x16x32_bf16(a, b0, acc[tap][mt][0], 0, 0, 0);
            acc[tap][mt][1] = __builtin_amdgcn_mfma_f32_16x16x32_bf16(a, b1, acc[tap][mt][1], 0, 0, 0);
        }
    }

    // Store P[gr][tap*128 + f] bf16 (verified C mapping row=quad*4+reg, col=lc).
#pragma unroll
    for (int tap = 0; tap < 3; ++tap)
#pragma unroll
        for (int mt = 0; mt < 4; ++mt) {
            int grb = row0 + mt * 16 + quad * 4;
#pragma unroll
            for (int nt = 0; nt < 2; ++nt) {
                int col = tap * 128 + (wn * 2 + nt) * 16 + lc;
#pragma unroll
                for (int reg = 0; reg < 4; ++reg) {
                    int gr = grb + reg;
                    if (gr < VOCAB)
                        P[(size_t)gr * 384 + col] = (unsigned short)f2bf1(acc[tap][mt][nt][reg]);
                }
            }
        }
}

// Fused gather + pool + FC: 512 blocks, one per batch row; 1024 threads =
// 16 waves (2 blocks/CU -> full 32-wave residency, one dispatch round).
// f = tid&127, half = tid>>7 (8 position slots per pass). Per position: 3 bf16
// lookups into L3-resident P (each wave reads 64 consecutive bf16 = one 128 B
// line per tap — zero amplification), fp32 sum, masked 3-segment max in
// registers. Then in-block: 8-half-plane reduce, bias+ReLU, FC 384->53 (the
// verified combine code). No Pd, no cross-block sync, no fences.
// All exports use guards valid for 1024 threads (r12 lesson).
__launch_bounds__(1024)
__global__ void pcnn_gather_fc(const int* __restrict__ cid, const int* __restrict__ p1,
                               const int* __restrict__ p2,
                               const unsigned short* __restrict__ P,
                               const float* __restrict__ cb,
                               const float* __restrict__ fcw,
                               const float* __restrict__ fcb,
                               float* __restrict__ out) {
    __shared__ int idsB[514];             // idsB[i] = P-row byte offset at pos i-1
    __shared__ float pstage[8][3][128];   // 12 KB
    __shared__ float pooled[384];
    __shared__ float fcred[NUMC][4];

    const int b   = blockIdx.x;
    const int tid = threadIdx.x;

    const int* crow = cid + (size_t)b * SEQ;
    for (int i = tid; i < 514; i += 1024) {
        int p = i - 1;
        unsigned int id = (p >= 0 && p < SEQ) ? (unsigned int)crow[p] : 0u;
        idsB[i] = (int)(id * 768u);       // 384 cols x 2 B
    }

    int e1 = min(p1[b], p2[b]);
    int e2 = max(p1[b], p2[b]);
    if (e1 == e2) e2 = min(e1 + 1, SEQ);
    const int e1m = max(e1, 1);

    __syncthreads();

    const int f    = tid & 127;
    const int half = tid >> 7;            // 0..7
    const char* Pb = (const char*)P;
    const int o0 = f * 2;                 // tap 0: id at l-1
    const int o1 = 256 + f * 2;           // tap 1: id at l
    const int o2 = 512 + f * 2;           // tap 2: id at l+1

    float smax0 = -1e30f, smax1 = -1e30f, smax2 = -1e30f;

#pragma unroll 4
    for (int pass = 0; pass < 64; ++pass) {
        int p = pass * 8 + half;          // position 0..511
        float v = b2f(*(const unsigned short*)(Pb + idsB[p]     + o0))
                + b2f(*(const unsigned short*)(Pb + idsB[p + 1] + o1))
                + b2f(*(const unsigned short*)(Pb + idsB[p + 2] + o2));
        smax0 = fmaxf(smax0, v + ((p < e1m)           ? 0.f : -2e30f));
        smax1 = fmaxf(smax1, v + ((p >= e1 && p < e2) ? 0.f : -2e30f));
        smax2 = fmaxf(smax2, v + ((p >= e2)           ? 0.f : -2e30f));
    }

    pstage[half][0][f] = smax0;
    pstage[half][1][f] = smax1;
    pstage[half][2][f] = smax2;
    __syncthreads();

    // Reduce 8 half-planes -> pooled[384] with bias+ReLU (tid<384 < 1024: full cover).
    if (tid < 384) {
        int s3 = tid >> 7, ff = tid & 127;
        float m = pstage[0][s3][ff];
#pragma unroll
        for (int h = 1; h < 8; ++h) m = fmaxf(m, pstage[h][s3][ff]);
        pooled[tid] = fmaxf(m + cb[ff], 0.f);
    }
    __syncthreads();

    // FC 384 -> 53 (verified combine code; summation order preserved).
    if (tid < 212) {
        int c = tid >> 2, q = tid & 3;
        const float* wrow = fcw + (size_t)c * 384 + q * 96;
        const float* pp   = pooled + q * 96;
        float sum = 0.f;
#pragma unroll 8
        for (int i = 0; i < 96; ++i) sum += wrow[i] * pp[i];
        fcred[c][q] = sum;
    }
    __syncthreads();
    if (tid < NUMC)
        out[(size_t)b * NUMC + tid] =
            fcred[tid][0] + fcred[tid][1] + fcred[tid][2] + fcred[tid][3] + fcb[tid];
}

extern "C" void kernel_launch(void* const* d_in, const int* in_sizes, int n_in,
                              void* d_out, int out_size, void* d_ws, size_t ws_size,
                              hipStream_t stream) {
    const int*   cid = (const int*)d_in[0];
    const int*   p1  = (const int*)d_in[1];
    const int*   p2  = (const int*)d_in[2];
    const float* emb = (const float*)d_in[3];
    const float* cw  = (const float*)d_in[4];
    const float* cb  = (const float*)d_in[5];
    const float* fcw = (const float*)d_in[6];
    const float* fcb = (const float*)d_in[7];
    float* out = (float*)d_out;

    // ws: Wp bf16 [49152] (98,304 B) | P bf16 [VOCAB*384] (16,226,304 B)
    unsigned short* Wp = (unsigned short*)d_ws;
    unsigned short* P  = (unsigned short*)((char*)d_ws + 98304);

    const int gemm_blocks = (VOCAB + 63) / 64;  // 331
    prep_w<<<192, 256, 0, stream>>>(cw, Wp);
    pcnn_vgemm<<<gemm_blocks, 256, 0, stream>>>(emb, Wp, P);
    pcnn_gather_fc<<<BATCH, 1024, 0, stream>>>(cid, p1, p2, P, cb, fcw, fcb, out);
}